// Round 1
// baseline (108.071 us; speedup 1.0000x reference)
//
#include <hip/hip_runtime.h>
#include <math.h>

#define NJ 7
#define DTF 0.01f
#define GRAVF 9.81f

__device__ __forceinline__ void cross3(const float* a, const float* b, float* o){
    o[0] = a[1]*b[2] - a[2]*b[1];
    o[1] = a[2]*b[0] - a[0]*b[2];
    o[2] = a[0]*b[1] - a[1]*b[0];
}
// y = E @ x  (3x3 row-major)
__device__ __forceinline__ void mv3(const float* E, const float* x, float* y){
    y[0] = E[0]*x[0] + E[1]*x[1] + E[2]*x[2];
    y[1] = E[3]*x[0] + E[4]*x[1] + E[5]*x[2];
    y[2] = E[6]*x[0] + E[7]*x[1] + E[8]*x[2];
}
// y = E^T @ x
__device__ __forceinline__ void mtv3(const float* E, const float* x, float* y){
    y[0] = E[0]*x[0] + E[3]*x[1] + E[6]*x[2];
    y[1] = E[1]*x[0] + E[4]*x[1] + E[7]*x[2];
    y[2] = E[2]*x[0] + E[5]*x[1] + E[8]*x[2];
}
// o = A @ B
__device__ __forceinline__ void mm3(const float* A, const float* B, float* o){
#pragma unroll
    for (int r = 0; r < 3; r++){
#pragma unroll
        for (int c = 0; c < 3; c++){
            o[r*3+c] = A[r*3]*B[c] + A[r*3+1]*B[3+c] + A[r*3+2]*B[6+c];
        }
    }
}
// o = E^T @ X @ E
__device__ __forceinline__ void congr(const float* E, const float* X, float* o){
    float t[9];
#pragma unroll
    for (int r = 0; r < 3; r++){
#pragma unroll
        for (int c = 0; c < 3; c++){
            t[r*3+c] = E[r]*X[c] + E[3+r]*X[3+c] + E[6+r]*X[6+c];
        }
    }
    mm3(t, E, o);
}
// o = X @ skew(p): row_r(o) = row_r(X) x p
__device__ __forceinline__ void mskew(const float* X, const float* p, float* o){
#pragma unroll
    for (int r = 0; r < 3; r++) cross3(X + r*3, p, o + r*3);
}
// o = skew(p) @ X: col_c(o) = p x col_c(X)
__device__ __forceinline__ void skewm(const float* p, const float* X, float* o){
#pragma unroll
    for (int c = 0; c < 3; c++){
        o[c]   = p[1]*X[6+c] - p[2]*X[3+c];
        o[3+c] = p[2]*X[c]   - p[0]*X[6+c];
        o[6+c] = p[0]*X[3+c] - p[1]*X[c];
    }
}

__global__ __launch_bounds__(256)
void panda_step(const float* __restrict__ x, const float* __restrict__ u,
                const float* __restrict__ g_ax, const float* __restrict__ g_Rt,
                const float* __restrict__ g_pt, const float* __restrict__ g_I,
                float* __restrict__ out, int B)
{
    __shared__ float s_ax[NJ*3];
    __shared__ float s_Rt[NJ*9];
    __shared__ float s_pt[NJ*3];
    __shared__ float s_I[NJ*36];
    for (int i = threadIdx.x; i < NJ*3; i += blockDim.x){ s_ax[i] = g_ax[i]; s_pt[i] = g_pt[i]; }
    for (int i = threadIdx.x; i < NJ*9; i += blockDim.x) s_Rt[i] = g_Rt[i];
    for (int i = threadIdx.x; i < NJ*36; i += blockDim.x) s_I[i] = g_I[i];
    __syncthreads();

    int b = blockIdx.x*blockDim.x + threadIdx.x;
    if (b >= B) return;

    const float QL[NJ] = {-2.9671f,-1.8326f,-2.9671f,-3.1416f,-2.9671f,-0.0873f,-2.9671f};
    const float QU[NJ] = { 2.9671f, 1.8326f, 2.9671f, 0.0f,    2.9671f, 3.8223f, 2.9671f};

    float q[NJ], qd[NJ];
#pragma unroll
    for (int i = 0; i < NJ; i++){
        float qi = x[b*14 + i];
        q[i]  = fminf(fmaxf(qi, QL[i]), QU[i]);
        qd[i] = x[b*14 + NJ + i];
    }

    // E_i = R(q_i)^T @ R_tree[i]; Xup_i == mot_X(E_i, p_tree[i])
    float E[NJ][9];
#pragma unroll
    for (int i = 0; i < NJ; i++){
        const float* a = &s_ax[i*3];
        float s, c;
        sincosf(q[i], &s, &c);
        float omc = 1.0f - c;
        float RT[9];
        RT[0] = c + omc*a[0]*a[0];       RT[1] =  s*a[2] + omc*a[0]*a[1]; RT[2] = -s*a[1] + omc*a[0]*a[2];
        RT[3] = -s*a[2] + omc*a[1]*a[0]; RT[4] = c + omc*a[1]*a[1];       RT[5] =  s*a[0] + omc*a[1]*a[2];
        RT[6] =  s*a[1] + omc*a[2]*a[0]; RT[7] = -s*a[0] + omc*a[2]*a[1]; RT[8] = c + omc*a[2]*a[2];
        mm3(RT, &s_Rt[i*9], &E[i][0]);
    }

    // ---- forward pass (RNEA bias forces) ----
    float f[NJ][6];
    float w[3]  = {0.f, 0.f, 0.f};
    float vl[3] = {0.f, 0.f, 0.f};
    float aw[3] = {0.f, 0.f, 0.f};
    float av[3] = {0.f, 0.f, GRAVF};
#pragma unroll
    for (int i = 0; i < NJ; i++){
        const float* a  = &s_ax[i*3];
        const float* p  = &s_pt[i*3];
        const float* Ei = &E[i][0];
        float qdi = qd[i];
        // v_new = Xup v_prev + S qd
        float tw[3]; mv3(Ei, w, tw);
        float nw[3] = { tw[0] + a[0]*qdi, tw[1] + a[1]*qdi, tw[2] + a[2]*qdi };
        float cwp[3]; cross3(w, p, cwp);
        float t1[3] = { vl[0]+cwp[0], vl[1]+cwp[1], vl[2]+cwp[2] };
        float nvl[3]; mv3(Ei, t1, nvl);
        // acc_new = Xup a_prev + crm(v_new) @ (S qd)
        float taw[3]; mv3(Ei, aw, taw);
        float cna[3]; cross3(nw, a, cna);
        float naw[3] = { taw[0] + qdi*cna[0], taw[1] + qdi*cna[1], taw[2] + qdi*cna[2] };
        float cap[3]; cross3(aw, p, cap);
        float t2[3] = { av[0]+cap[0], av[1]+cap[1], av[2]+cap[2] };
        float tav[3]; mv3(Ei, t2, tav);
        float cva[3]; cross3(nvl, a, cva);
        float nav[3] = { tav[0] + qdi*cva[0], tav[1] + qdi*cva[1], tav[2] + qdi*cva[2] };
        // f = I acc + [w x Iv_t + vl x Iv_b ; w x Iv_b]
        const float* Ii = &s_I[i*36];
        float v6[6] = { nw[0], nw[1], nw[2], nvl[0], nvl[1], nvl[2] };
        float a6[6] = { naw[0], naw[1], naw[2], nav[0], nav[1], nav[2] };
        float Iv[6], Ia[6];
#pragma unroll
        for (int r = 0; r < 6; r++){
            float s1 = 0.f, s2 = 0.f;
#pragma unroll
            for (int k = 0; k < 6; k++){ s1 += Ii[r*6+k]*v6[k]; s2 += Ii[r*6+k]*a6[k]; }
            Iv[r] = s1; Ia[r] = s2;
        }
        float c1[3], c2[3], c3[3];
        cross3(nw, &Iv[0], c1);
        cross3(nvl, &Iv[3], c2);
        cross3(nw, &Iv[3], c3);
        f[i][0] = Ia[0] + c1[0] + c2[0];
        f[i][1] = Ia[1] + c1[1] + c2[1];
        f[i][2] = Ia[2] + c1[2] + c2[2];
        f[i][3] = Ia[3] + c3[0];
        f[i][4] = Ia[4] + c3[1];
        f[i][5] = Ia[5] + c3[2];
#pragma unroll
        for (int k = 0; k < 3; k++){ w[k]=nw[k]; vl[k]=nvl[k]; aw[k]=naw[k]; av[k]=nav[k]; }
    }

    // ---- backward pass: h, propagate forces ----
    float h[NJ];
#pragma unroll
    for (int i = NJ-1; i >= 0; i--){
        const float* a = &s_ax[i*3];
        h[i] = a[0]*f[i][0] + a[1]*f[i][1] + a[2]*f[i][2];
        if (i > 0){
            const float* Ei = &E[i][0];
            const float* p  = &s_pt[i*3];
            float tm[3], tf[3], cp[3];
            mtv3(Ei, &f[i][0], tm);
            mtv3(Ei, &f[i][3], tf);
            cross3(p, tf, cp);
            f[i-1][0] += tm[0] + cp[0];
            f[i-1][1] += tm[1] + cp[1];
            f[i-1][2] += tm[2] + cp[2];
            f[i-1][3] += tf[0];
            f[i-1][4] += tf[1];
            f[i-1][5] += tf[2];
        }
    }

    // ---- CRBA: mass matrix ----
    float Ic[36];
#pragma unroll
    for (int k = 0; k < 36; k++) Ic[k] = s_I[6*36 + k];
    float M[NJ][NJ];
#pragma unroll
    for (int i = NJ-1; i >= 0; i--){
        const float* ai = &s_ax[i*3];
        float F[6];
#pragma unroll
        for (int r = 0; r < 6; r++)
            F[r] = Ic[r*6+0]*ai[0] + Ic[r*6+1]*ai[1] + Ic[r*6+2]*ai[2];
        M[i][i] = ai[0]*F[0] + ai[1]*F[1] + ai[2]*F[2];
#pragma unroll
        for (int j = i-1; j >= 0; j--){
            const float* Ej = &E[j+1][0];
            const float* pj = &s_pt[(j+1)*3];
            float tm[3], tf[3], cp[3];
            mtv3(Ej, &F[0], tm);
            mtv3(Ej, &F[3], tf);
            cross3(pj, tf, cp);
            F[0] = tm[0] + cp[0]; F[1] = tm[1] + cp[1]; F[2] = tm[2] + cp[2];
            F[3] = tf[0]; F[4] = tf[1]; F[5] = tf[2];
            const float* aj = &s_ax[j*3];
            float mij = aj[0]*F[0] + aj[1]*F[1] + aj[2]*F[2];
            M[i][j] = mij; M[j][i] = mij;
        }
        if (i > 0){
            const float* Ei = &E[i][0];
            const float* p  = &s_pt[i*3];
            // blocks of Ic (6x6 row-major): A=[0:3,0:3] B=[0:3,3:6] C=[3:6,0:3] D=[3:6,3:6]
            float A[9], Bb[9], Cc[9], Dd[9];
#pragma unroll
            for (int r = 0; r < 3; r++){
#pragma unroll
                for (int c = 0; c < 3; c++){
                    A[r*3+c]  = Ic[r*6+c];
                    Bb[r*3+c] = Ic[r*6+3+c];
                    Cc[r*3+c] = Ic[(r+3)*6+c];
                    Dd[r*3+c] = Ic[(r+3)*6+3+c];
                }
            }
            float Ap[9], Bp[9], Cp[9], Dp[9];
            congr(Ei, A,  Ap);
            congr(Ei, Bb, Bp);
            congr(Ei, Cc, Cp);
            congr(Ei, Dd, Dp);
            float BpP[9], PCp[9], DpP[9], PDpP[9], PDp[9];
            mskew(Bp, p, BpP);
            skewm(p, Cp, PCp);
            mskew(Dp, p, DpP);
            skewm(p, DpP, PDpP);
            skewm(p, Dp, PDp);
            const float* In = &s_I[(i-1)*36];
#pragma unroll
            for (int r = 0; r < 3; r++){
#pragma unroll
                for (int c = 0; c < 3; c++){
                    Ic[r*6+c]       = In[r*6+c]       + Ap[r*3+c] - BpP[r*3+c] + PCp[r*3+c] - PDpP[r*3+c];
                    Ic[r*6+3+c]     = In[r*6+3+c]     + Bp[r*3+c] + PDp[r*3+c];
                    Ic[(r+3)*6+c]   = In[(r+3)*6+c]   + Cp[r*3+c] - DpP[r*3+c];
                    Ic[(r+3)*6+3+c] = In[(r+3)*6+3+c] + Dp[r*3+c];
                }
            }
        }
    }
#pragma unroll
    for (int i = 0; i < NJ; i++) M[i][i] += 1e-8f;

    // ---- solve M qdd = u - h  (Cholesky, M SPD) ----
    float rhs[NJ];
#pragma unroll
    for (int i = 0; i < NJ; i++) rhs[i] = u[b*NJ + i] - h[i];

#pragma unroll
    for (int k = 0; k < NJ; k++){
        float d = M[k][k];
#pragma unroll
        for (int j = 0; j < NJ; j++) if (j < k) d -= M[k][j]*M[k][j];
        d = sqrtf(d);
        M[k][k] = d;
        float inv = 1.0f / d;
#pragma unroll
        for (int i = 0; i < NJ; i++) if (i > k){
            float s2 = M[i][k];
#pragma unroll
            for (int j = 0; j < NJ; j++) if (j < k) s2 -= M[i][j]*M[k][j];
            M[i][k] = s2 * inv;
        }
    }
    float y[NJ];
#pragma unroll
    for (int i = 0; i < NJ; i++){
        float s2 = rhs[i];
#pragma unroll
        for (int j = 0; j < NJ; j++) if (j < i) s2 -= M[i][j]*y[j];
        y[i] = s2 / M[i][i];
    }
    float z[NJ];
#pragma unroll
    for (int i = NJ-1; i >= 0; i--){
        float s2 = y[i];
#pragma unroll
        for (int j = 0; j < NJ; j++) if (j > i) s2 -= M[j][i]*z[j];
        z[i] = s2 / M[i][i];
    }

#pragma unroll
    for (int i = 0; i < NJ; i++){
        float qdn = qd[i] + DTF*z[i];
        float qn  = q[i]  + DTF*qdn;
        out[b*14 + i]      = qn;
        out[b*14 + NJ + i] = qdn;
    }
}

extern "C" void kernel_launch(void* const* d_in, const int* in_sizes, int n_in,
                              void* d_out, int out_size, void* d_ws, size_t ws_size,
                              hipStream_t stream) {
    const float* x   = (const float*)d_in[0];
    const float* u   = (const float*)d_in[1];
    const float* ax  = (const float*)d_in[2];
    const float* Rt  = (const float*)d_in[3];
    const float* pt  = (const float*)d_in[4];
    const float* Isp = (const float*)d_in[5];
    float* out = (float*)d_out;
    int B = in_sizes[0] / 14;
    int block = 256;
    int grid = (B + block - 1) / block;
    hipLaunchKernelGGL(panda_step, dim3(grid), dim3(block), 0, stream,
                       x, u, ax, Rt, pt, Isp, out, B);
}

// Round 2
// 92.672 us; speedup vs baseline: 1.1662x; 1.1662x over previous
//
#include <hip/hip_runtime.h>
#include <math.h>

#define NJ 7
#define DTF 0.01f
#define GRAVF 9.81f
#define MIX(i,j) ((i)*((i)+1)/2 + (j))

__device__ __forceinline__ void cross3(const float* a, const float* b, float* o){
    o[0] = a[1]*b[2] - a[2]*b[1];
    o[1] = a[2]*b[0] - a[0]*b[2];
    o[2] = a[0]*b[1] - a[1]*b[0];
}
// y = E @ x (3x3 row-major)
__device__ __forceinline__ void mv3(const float* E, const float* x, float* y){
    y[0] = E[0]*x[0] + E[1]*x[1] + E[2]*x[2];
    y[1] = E[3]*x[0] + E[4]*x[1] + E[5]*x[2];
    y[2] = E[6]*x[0] + E[7]*x[1] + E[8]*x[2];
}
// y = E^T @ x
__device__ __forceinline__ void mtv3(const float* E, const float* x, float* y){
    y[0] = E[0]*x[0] + E[3]*x[1] + E[6]*x[2];
    y[1] = E[1]*x[0] + E[4]*x[1] + E[7]*x[2];
    y[2] = E[2]*x[0] + E[5]*x[1] + E[8]*x[2];
}
// o = A @ B
__device__ __forceinline__ void mm3(const float* A, const float* B, float* o){
#pragma unroll
    for (int r = 0; r < 3; r++){
#pragma unroll
        for (int c = 0; c < 3; c++){
            o[r*3+c] = A[r*3]*B[c] + A[r*3+1]*B[3+c] + A[r*3+2]*B[6+c];
        }
    }
}
// o = E^T @ X @ E
__device__ __forceinline__ void congr(const float* E, const float* X, float* o){
    float t[9];
#pragma unroll
    for (int r = 0; r < 3; r++){
#pragma unroll
        for (int c = 0; c < 3; c++){
            t[r*3+c] = E[r]*X[c] + E[3+r]*X[3+c] + E[6+r]*X[6+c];
        }
    }
    mm3(t, E, o);
}

__global__ __launch_bounds__(256)
void panda_step(const float* __restrict__ x, const float* __restrict__ u,
                const float* __restrict__ g_ax, const float* __restrict__ g_Rt,
                const float* __restrict__ g_pt, const float* __restrict__ g_I,
                float* __restrict__ out, int B)
{
    // Constants in LDS. Spatial inertia decomposed: A = top-left 3x3 (sym, stored
    // full for cheap mv3), h (first moment, from skew in top-right block), m.
    __shared__ float s_ax[NJ*3], s_Rt[NJ*9], s_pt[NJ*3], s_A[NJ*9], s_h[NJ*3], s_m[NJ];
    if (threadIdx.x < NJ){
        int i = threadIdx.x;
#pragma unroll
        for (int k = 0; k < 3; k++){ s_ax[i*3+k] = g_ax[i*3+k]; s_pt[i*3+k] = g_pt[i*3+k]; }
#pragma unroll
        for (int k = 0; k < 9; k++) s_Rt[i*9+k] = g_Rt[i*9+k];
        const float* I6 = g_I + i*36;
#pragma unroll
        for (int r = 0; r < 3; r++)
#pragma unroll
            for (int c = 0; c < 3; c++) s_A[i*9+r*3+c] = I6[r*6+c];
        s_h[i*3+0] = I6[2*6+3+1];  // B[2][1] =  h0
        s_h[i*3+1] = I6[0*6+3+2];  // B[0][2] =  h1
        s_h[i*3+2] = I6[1*6+3+0];  // B[1][0] =  h2
        s_m[i]     = I6[3*6+3];    // D[0][0] =  m
    }
    __syncthreads();

    int b = blockIdx.x*blockDim.x + threadIdx.x;
    if (b >= B) return;

    const float QL[NJ] = {-2.9671f,-1.8326f,-2.9671f,-3.1416f,-2.9671f,-0.0873f,-2.9671f};
    const float QU[NJ] = { 2.9671f, 1.8326f, 2.9671f, 0.0f,    2.9671f, 3.8223f, 2.9671f};

    // x: 14 floats, 56B-aligned per row -> float2 loads
    float xl[14];
    {
        const float2* x2 = (const float2*)(x + b*14);
#pragma unroll
        for (int i = 0; i < 7; i++){ float2 v = x2[i]; xl[2*i] = v.x; xl[2*i+1] = v.y; }
    }
    float q[NJ], qd[NJ], sn[NJ], cs[NJ];
#pragma unroll
    for (int i = 0; i < NJ; i++){
        q[i]  = fminf(fmaxf(xl[i], QL[i]), QU[i]);
        qd[i] = xl[NJ + i];
        __sincosf(q[i], &sn[i], &cs[i]);
    }
    float rhs[NJ];
#pragma unroll
    for (int i = 0; i < NJ; i++) rhs[i] = u[b*NJ + i];

    // E_i = R(q_i)^T @ R_tree[i]; Xup_i = [[E,0],[-E*skew(p),E]]
    auto makeE = [&](int i, float* Eo){
        const float* a = &s_ax[i*3];
        float s = sn[i], c = cs[i], omc = 1.0f - c;
        float RT[9];
        RT[0] = c + omc*a[0]*a[0];       RT[1] =  s*a[2] + omc*a[0]*a[1]; RT[2] = -s*a[1] + omc*a[0]*a[2];
        RT[3] = -s*a[2] + omc*a[1]*a[0]; RT[4] = c + omc*a[1]*a[1];       RT[5] =  s*a[0] + omc*a[1]*a[2];
        RT[6] =  s*a[1] + omc*a[2]*a[0]; RT[7] = -s*a[0] + omc*a[2]*a[1]; RT[8] = c + omc*a[2]*a[2];
        mm3(RT, &s_Rt[i*9], Eo);
    };

    // ---- forward pass (RNEA bias forces) ----
    // FF[i] holds bias force f_i now; re-used as CRBA F_i later.
    float FF[NJ][6];
    float w[3]  = {0.f,0.f,0.f}, vl[3] = {0.f,0.f,0.f};
    float aw[3] = {0.f,0.f,0.f}, av[3] = {0.f,0.f,GRAVF};
#pragma unroll
    for (int i = 0; i < NJ; i++){
        const float* a = &s_ax[i*3];
        const float* p = &s_pt[i*3];
        float E[9]; makeE(i, E);
        float qdi = qd[i];
        float tw[3]; mv3(E, w, tw);
        float nw[3] = { tw[0]+a[0]*qdi, tw[1]+a[1]*qdi, tw[2]+a[2]*qdi };
        float cwp[3]; cross3(w, p, cwp);
        float t1[3] = { vl[0]+cwp[0], vl[1]+cwp[1], vl[2]+cwp[2] };
        float nvl[3]; mv3(E, t1, nvl);
        float taw[3]; mv3(E, aw, taw);
        float cna[3]; cross3(nw, a, cna);
        float naw[3] = { taw[0]+qdi*cna[0], taw[1]+qdi*cna[1], taw[2]+qdi*cna[2] };
        float cap[3]; cross3(aw, p, cap);
        float t2[3] = { av[0]+cap[0], av[1]+cap[1], av[2]+cap[2] };
        float tav[3]; mv3(E, t2, tav);
        float cva[3]; cross3(nvl, a, cva);
        float nav[3] = { tav[0]+qdi*cva[0], tav[1]+qdi*cva[1], tav[2]+qdi*cva[2] };
        // I@v with structured inertia: top = A w + h x vl ; bot = m vl - h x w
        const float* Ai = &s_A[i*9];
        const float* hi = &s_h[i*3];
        float mi = s_m[i];
        float Ivt[3], Iat[3], hxv[3], hxa[3];
        mv3(Ai, nw, Ivt);  cross3(hi, nvl, hxv);
        mv3(Ai, naw, Iat); cross3(hi, nav, hxa);
#pragma unroll
        for (int k = 0; k < 3; k++){ Ivt[k] += hxv[k]; Iat[k] += hxa[k]; }
        float hxw[3], hxaw[3];
        cross3(hi, nw, hxw); cross3(hi, naw, hxaw);
        float Ivb[3] = { mi*nvl[0]-hxw[0], mi*nvl[1]-hxw[1], mi*nvl[2]-hxw[2] };
        float Iab[3] = { mi*nav[0]-hxaw[0], mi*nav[1]-hxaw[1], mi*nav[2]-hxaw[2] };
        float c1[3], c2[3], c3[3];
        cross3(nw, Ivt, c1); cross3(nvl, Ivb, c2); cross3(nw, Ivb, c3);
        FF[i][0] = Iat[0]+c1[0]+c2[0];
        FF[i][1] = Iat[1]+c1[1]+c2[1];
        FF[i][2] = Iat[2]+c1[2]+c2[2];
        FF[i][3] = Iab[0]+c3[0];
        FF[i][4] = Iab[1]+c3[1];
        FF[i][5] = Iab[2]+c3[2];
#pragma unroll
        for (int k = 0; k < 3; k++){ w[k]=nw[k]; vl[k]=nvl[k]; aw[k]=naw[k]; av[k]=nav[k]; }
    }

    // ---- fused descending sweep: RNEA backward + CRBA column sweep ----
    // Composite inertia params (frame-local): SA sym6, hc, mc.
    float SA[6], hc[3], mc;
    {
        const float* A6 = &s_A[6*9];
        SA[0]=A6[0]; SA[1]=A6[1]; SA[2]=A6[2]; SA[3]=A6[4]; SA[4]=A6[5]; SA[5]=A6[8];
        hc[0]=s_h[18]; hc[1]=s_h[19]; hc[2]=s_h[20];
        mc = s_m[6];
    }
    float Mx[28];
#pragma unroll
    for (int i = NJ-1; i >= 0; i--){
        const float* a = &s_ax[i*3];
        const float* p = &s_pt[i*3];
        float E[9]; makeE(i, E);
        // rhs[i] = u_i - h_i,  h_i = a . f_i_top
        rhs[i] -= a[0]*FF[i][0] + a[1]*FF[i][1] + a[2]*FF[i][2];
        if (i > 0){
            // fold bias force into parent: f_{i-1} += Xup_i^T f_i
            float tm[3], tf[3], cp[3];
            mtv3(E, &FF[i][0], tm); mtv3(E, &FF[i][3], tf);
            cross3(p, tf, cp);
            FF[i-1][0]+=tm[0]+cp[0]; FF[i-1][1]+=tm[1]+cp[1]; FF[i-1][2]+=tm[2]+cp[2];
            FF[i-1][3]+=tf[0];       FF[i-1][4]+=tf[1];       FF[i-1][5]+=tf[2];
        }
        // F_i = Ic @ S_i = [A a ; a x h]  (overwrite slot i, bias consumed)
        FF[i][0] = SA[0]*a[0] + SA[1]*a[1] + SA[2]*a[2];
        FF[i][1] = SA[1]*a[0] + SA[3]*a[1] + SA[4]*a[2];
        FF[i][2] = SA[2]*a[0] + SA[4]*a[1] + SA[5]*a[2];
        FF[i][3] = a[1]*hc[2] - a[2]*hc[1];
        FF[i][4] = a[2]*hc[0] - a[0]*hc[2];
        FF[i][5] = a[0]*hc[1] - a[1]*hc[0];
        Mx[MIX(i,i)] = a[0]*FF[i][0] + a[1]*FF[i][1] + a[2]*FF[i][2];
#pragma unroll
        for (int k = i+1; k < NJ; k++)
            Mx[MIX(k,i)] = a[0]*FF[k][0] + a[1]*FF[k][1] + a[2]*FF[k][2];
        if (i > 0){
            // Ic' = I_{i-1} + Xup^T Ic Xup in 10-param form:
            // A' = E^T A E - p h'^T - h' p^T - m p p^T + (2 h'.p + m p.p) I ; h' = E^T h + m p
            float Af[9] = {SA[0],SA[1],SA[2], SA[1],SA[3],SA[4], SA[2],SA[4],SA[5]};
            float Ap[9]; congr(E, Af, Ap);
            float hr[3]; mtv3(E, hc, hr);
            float hpd = hr[0]*p[0]+hr[1]*p[1]+hr[2]*p[2];
            float ppd = p[0]*p[0]+p[1]*p[1]+p[2]*p[2];
            float dga = 2.0f*hpd + mc*ppd;
            const float* An = &s_A[(i-1)*9];
            SA[0] = Ap[0] - 2.0f*p[0]*hr[0] - mc*p[0]*p[0] + dga + An[0];
            SA[1] = Ap[1] - p[0]*hr[1] - hr[0]*p[1] - mc*p[0]*p[1] + An[1];
            SA[2] = Ap[2] - p[0]*hr[2] - hr[0]*p[2] - mc*p[0]*p[2] + An[2];
            SA[3] = Ap[4] - 2.0f*p[1]*hr[1] - mc*p[1]*p[1] + dga + An[4];
            SA[4] = Ap[5] - p[1]*hr[2] - hr[1]*p[2] - mc*p[1]*p[2] + An[5];
            SA[5] = Ap[8] - 2.0f*p[2]*hr[2] - mc*p[2]*p[2] + dga + An[8];
            hc[0] = hr[0] + mc*p[0] + s_h[(i-1)*3+0];
            hc[1] = hr[1] + mc*p[1] + s_h[(i-1)*3+1];
            hc[2] = hr[2] + mc*p[2] + s_h[(i-1)*3+2];
            mc += s_m[i-1];
            // transform all active F_k into frame i-1
#pragma unroll
            for (int k = i; k < NJ; k++){
                float tm[3], tf[3], cp[3];
                mtv3(E, &FF[k][0], tm); mtv3(E, &FF[k][3], tf);
                cross3(p, tf, cp);
                FF[k][0]=tm[0]+cp[0]; FF[k][1]=tm[1]+cp[1]; FF[k][2]=tm[2]+cp[2];
                FF[k][3]=tf[0];       FF[k][4]=tf[1];       FF[k][5]=tf[2];
            }
        }
    }
#pragma unroll
    for (int i = 0; i < NJ; i++) Mx[MIX(i,i)] += 1e-8f;

    // ---- Cholesky solve (diag slots hold 1/L_kk) ----
#pragma unroll
    for (int k = 0; k < NJ; k++){
        float d = Mx[MIX(k,k)];
#pragma unroll
        for (int j = 0; j < NJ; j++) if (j < k) d -= Mx[MIX(k,j)]*Mx[MIX(k,j)];
        float linv = __builtin_amdgcn_rsqf(d);
        Mx[MIX(k,k)] = linv;
#pragma unroll
        for (int i = k+1; i < NJ; i++){
            float s2 = Mx[MIX(i,k)];
#pragma unroll
            for (int j = 0; j < NJ; j++) if (j < k) s2 -= Mx[MIX(i,j)]*Mx[MIX(k,j)];
            Mx[MIX(i,k)] = s2 * linv;
        }
    }
    float y[NJ];
#pragma unroll
    for (int i = 0; i < NJ; i++){
        float s2 = rhs[i];
#pragma unroll
        for (int j = 0; j < NJ; j++) if (j < i) s2 -= Mx[MIX(i,j)]*y[j];
        y[i] = s2 * Mx[MIX(i,i)];
    }
    float z[NJ];
#pragma unroll
    for (int i = NJ-1; i >= 0; i--){
        float s2 = y[i];
#pragma unroll
        for (int j = NJ-1; j >= 0; j--) if (j > i) s2 -= Mx[MIX(j,i)]*z[j];
        z[i] = s2 * Mx[MIX(i,i)];
    }

    float o14[14];
#pragma unroll
    for (int i = 0; i < NJ; i++){
        float qdn = qd[i] + DTF*z[i];
        o14[i]      = q[i] + DTF*qdn;
        o14[NJ + i] = qdn;
    }
    float2* o2 = (float2*)(out + b*14);
#pragma unroll
    for (int i = 0; i < 7; i++){ float2 v; v.x = o14[2*i]; v.y = o14[2*i+1]; o2[i] = v; }
}

extern "C" void kernel_launch(void* const* d_in, const int* in_sizes, int n_in,
                              void* d_out, int out_size, void* d_ws, size_t ws_size,
                              hipStream_t stream) {
    const float* x   = (const float*)d_in[0];
    const float* u   = (const float*)d_in[1];
    const float* ax  = (const float*)d_in[2];
    const float* Rt  = (const float*)d_in[3];
    const float* pt  = (const float*)d_in[4];
    const float* Isp = (const float*)d_in[5];
    float* out = (float*)d_out;
    int B = in_sizes[0] / 14;
    int block = 256;
    int grid = (B + block - 1) / block;
    hipLaunchKernelGGL(panda_step, dim3(grid), dim3(block), 0, stream,
                       x, u, ax, Rt, pt, Isp, out, B);
}

// Round 3
// 82.667 us; speedup vs baseline: 1.3073x; 1.1210x over previous
//
#include <hip/hip_runtime.h>
#include <math.h>

#define NJ 7
#define DTF 0.01f
#define GRAVF 9.81f
#define MIX(i,j) ((i)*((i)+1)/2 + (j))
#define MPAD 29   // 28 lower-tri floats padded to 29 (coprime with 32 banks)

__device__ __forceinline__ void cross3(const float* a, const float* b, float* o){
    o[0] = a[1]*b[2] - a[2]*b[1];
    o[1] = a[2]*b[0] - a[0]*b[2];
    o[2] = a[0]*b[1] - a[1]*b[0];
}
__device__ __forceinline__ void mv3(const float* E, const float* x, float* y){
    y[0] = E[0]*x[0] + E[1]*x[1] + E[2]*x[2];
    y[1] = E[3]*x[0] + E[4]*x[1] + E[5]*x[2];
    y[2] = E[6]*x[0] + E[7]*x[1] + E[8]*x[2];
}
__device__ __forceinline__ void mtv3(const float* E, const float* x, float* y){
    y[0] = E[0]*x[0] + E[3]*x[1] + E[6]*x[2];
    y[1] = E[1]*x[0] + E[4]*x[1] + E[7]*x[2];
    y[2] = E[2]*x[0] + E[5]*x[1] + E[8]*x[2];
}
__device__ __forceinline__ void mm3(const float* A, const float* B, float* o){
#pragma unroll
    for (int r = 0; r < 3; r++){
#pragma unroll
        for (int c = 0; c < 3; c++){
            o[r*3+c] = A[r*3]*B[c] + A[r*3+1]*B[3+c] + A[r*3+2]*B[6+c];
        }
    }
}
__device__ __forceinline__ void congr(const float* E, const float* X, float* o){
    float t[9];
#pragma unroll
    for (int r = 0; r < 3; r++){
#pragma unroll
        for (int c = 0; c < 3; c++){
            t[r*3+c] = E[r]*X[c] + E[3+r]*X[3+c] + E[6+r]*X[6+c];
        }
    }
    mm3(t, E, o);
}
// E_i = R(q_i)^T @ R_tree[i]
__device__ __forceinline__ void makeE(const float* a, float s, float c,
                                      const float* Rt, float* Eo){
    float omc = 1.0f - c;
    float RT[9];
    RT[0] = c + omc*a[0]*a[0];       RT[1] =  s*a[2] + omc*a[0]*a[1]; RT[2] = -s*a[1] + omc*a[0]*a[2];
    RT[3] = -s*a[2] + omc*a[1]*a[0]; RT[4] = c + omc*a[1]*a[1];       RT[5] =  s*a[0] + omc*a[1]*a[2];
    RT[6] =  s*a[1] + omc*a[2]*a[0]; RT[7] = -s*a[0] + omc*a[2]*a[1]; RT[8] = c + omc*a[2]*a[2];
    mm3(RT, Rt, Eo);
}

// Block = 128 threads = 2 waves handling the SAME 64 batch elements.
// Wave 0: RNEA (bias forces -> rhs), then Cholesky solve + output.
// Wave 1: CRBA (mass matrix) -> LDS.
__global__ __launch_bounds__(128)
void panda_step(const float* __restrict__ x, const float* __restrict__ u,
                const float* __restrict__ g_ax, const float* __restrict__ g_Rt,
                const float* __restrict__ g_pt, const float* __restrict__ g_I,
                float* __restrict__ out, int B)
{
    __shared__ float s_ax[NJ*3], s_Rt[NJ*9], s_pt[NJ*3], s_A[NJ*9], s_h[NJ*3], s_m[NJ];
    __shared__ float s_M[64*MPAD];
    if (threadIdx.x < NJ){
        int i = threadIdx.x;
#pragma unroll
        for (int k = 0; k < 3; k++){ s_ax[i*3+k] = g_ax[i*3+k]; s_pt[i*3+k] = g_pt[i*3+k]; }
#pragma unroll
        for (int k = 0; k < 9; k++) s_Rt[i*9+k] = g_Rt[i*9+k];
        const float* I6 = g_I + i*36;
#pragma unroll
        for (int r = 0; r < 3; r++)
#pragma unroll
            for (int c = 0; c < 3; c++) s_A[i*9+r*3+c] = I6[r*6+c];
        s_h[i*3+0] = I6[2*6+3+1];
        s_h[i*3+1] = I6[0*6+3+2];
        s_h[i*3+2] = I6[1*6+3+0];
        s_m[i]     = I6[3*6+3];
    }
    __syncthreads();

    const int role = threadIdx.x >> 6;      // wave-uniform
    const int lane = threadIdx.x & 63;
    const int e    = blockIdx.x*64 + lane;
    const bool act = (e < B);

    const float QL[NJ] = {-2.9671f,-1.8326f,-2.9671f,-3.1416f,-2.9671f,-0.0873f,-2.9671f};
    const float QU[NJ] = { 2.9671f, 1.8326f, 2.9671f, 0.0f,    2.9671f, 3.8223f, 2.9671f};

    float q[NJ], qd[NJ], sn[NJ], cs[NJ];
    if (act){
        float xl[14];
        const float2* x2 = (const float2*)(x + e*14);
#pragma unroll
        for (int i = 0; i < 7; i++){ float2 v = x2[i]; xl[2*i] = v.x; xl[2*i+1] = v.y; }
#pragma unroll
        for (int i = 0; i < NJ; i++){
            q[i]  = fminf(fmaxf(xl[i], QL[i]), QU[i]);
            qd[i] = xl[NJ + i];
            __sincosf(q[i], &sn[i], &cs[i]);
        }
    }

    float rhs[NJ];

    if (act && role == 1){
        // =================== CRBA: mass matrix ===================
        float SA[6], hc[3], mc;
        {
            const float* A6 = &s_A[6*9];
            SA[0]=A6[0]; SA[1]=A6[1]; SA[2]=A6[2]; SA[3]=A6[4]; SA[4]=A6[5]; SA[5]=A6[8];
            hc[0]=s_h[18]; hc[1]=s_h[19]; hc[2]=s_h[20];
            mc = s_m[6];
        }
        float Fk[NJ][6];
        float Mx[28];
#pragma unroll
        for (int i = NJ-1; i >= 0; i--){
            const float* a = &s_ax[i*3];
            const float* p = &s_pt[i*3];
            // F_i = Ic @ S_i = [A a ; a x h]
            Fk[i][0] = SA[0]*a[0] + SA[1]*a[1] + SA[2]*a[2];
            Fk[i][1] = SA[1]*a[0] + SA[3]*a[1] + SA[4]*a[2];
            Fk[i][2] = SA[2]*a[0] + SA[4]*a[1] + SA[5]*a[2];
            Fk[i][3] = a[1]*hc[2] - a[2]*hc[1];
            Fk[i][4] = a[2]*hc[0] - a[0]*hc[2];
            Fk[i][5] = a[0]*hc[1] - a[1]*hc[0];
#pragma unroll
            for (int k = i; k < NJ; k++)
                Mx[MIX(k,i)] = a[0]*Fk[k][0] + a[1]*Fk[k][1] + a[2]*Fk[k][2];
            if (i > 0){
                float E[9]; makeE(a, sn[i], cs[i], &s_Rt[i*9], E);
                // composite inertia congruence in 10-param form
                float Af[9] = {SA[0],SA[1],SA[2], SA[1],SA[3],SA[4], SA[2],SA[4],SA[5]};
                float Ap[9]; congr(E, Af, Ap);
                float hr[3]; mtv3(E, hc, hr);
                float hpd = hr[0]*p[0]+hr[1]*p[1]+hr[2]*p[2];
                float ppd = p[0]*p[0]+p[1]*p[1]+p[2]*p[2];
                float dga = 2.0f*hpd + mc*ppd;
                const float* An = &s_A[(i-1)*9];
                SA[0] = Ap[0] - 2.0f*p[0]*hr[0] - mc*p[0]*p[0] + dga + An[0];
                SA[1] = Ap[1] - p[0]*hr[1] - hr[0]*p[1] - mc*p[0]*p[1] + An[1];
                SA[2] = Ap[2] - p[0]*hr[2] - hr[0]*p[2] - mc*p[0]*p[2] + An[2];
                SA[3] = Ap[4] - 2.0f*p[1]*hr[1] - mc*p[1]*p[1] + dga + An[4];
                SA[4] = Ap[5] - p[1]*hr[2] - hr[1]*p[2] - mc*p[1]*p[2] + An[5];
                SA[5] = Ap[8] - 2.0f*p[2]*hr[2] - mc*p[2]*p[2] + dga + An[8];
                hc[0] = hr[0] + mc*p[0] + s_h[(i-1)*3+0];
                hc[1] = hr[1] + mc*p[1] + s_h[(i-1)*3+1];
                hc[2] = hr[2] + mc*p[2] + s_h[(i-1)*3+2];
                mc += s_m[i-1];
                // transform active F_k into frame i-1
#pragma unroll
                for (int k = i; k < NJ; k++){
                    float tm[3], tf[3], cp[3];
                    mtv3(E, &Fk[k][0], tm); mtv3(E, &Fk[k][3], tf);
                    cross3(p, tf, cp);
                    Fk[k][0]=tm[0]+cp[0]; Fk[k][1]=tm[1]+cp[1]; Fk[k][2]=tm[2]+cp[2];
                    Fk[k][3]=tf[0];       Fk[k][4]=tf[1];       Fk[k][5]=tf[2];
                }
            }
        }
#pragma unroll
        for (int j = 0; j < 28; j++) s_M[lane*MPAD + j] = Mx[j];
    }
    else if (act){
        // =================== RNEA: bias forces ===================
#pragma unroll
        for (int i = 0; i < NJ; i++) rhs[i] = u[e*NJ + i];
        float FF[NJ][6];
        float w[3]  = {0.f,0.f,0.f}, vl[3] = {0.f,0.f,0.f};
        float aw[3] = {0.f,0.f,0.f}, av[3] = {0.f,0.f,GRAVF};
#pragma unroll
        for (int i = 0; i < NJ; i++){
            const float* a = &s_ax[i*3];
            const float* p = &s_pt[i*3];
            float E[9]; makeE(a, sn[i], cs[i], &s_Rt[i*9], E);
            float qdi = qd[i];
            float tw[3]; mv3(E, w, tw);
            float nw[3] = { tw[0]+a[0]*qdi, tw[1]+a[1]*qdi, tw[2]+a[2]*qdi };
            float cwp[3]; cross3(w, p, cwp);
            float t1[3] = { vl[0]+cwp[0], vl[1]+cwp[1], vl[2]+cwp[2] };
            float nvl[3]; mv3(E, t1, nvl);
            float taw[3]; mv3(E, aw, taw);
            float cna[3]; cross3(nw, a, cna);
            float naw[3] = { taw[0]+qdi*cna[0], taw[1]+qdi*cna[1], taw[2]+qdi*cna[2] };
            float cap[3]; cross3(aw, p, cap);
            float t2[3] = { av[0]+cap[0], av[1]+cap[1], av[2]+cap[2] };
            float tav[3]; mv3(E, t2, tav);
            float cva[3]; cross3(nvl, a, cva);
            float nav[3] = { tav[0]+qdi*cva[0], tav[1]+qdi*cva[1], tav[2]+qdi*cva[2] };
            const float* Ai = &s_A[i*9];
            const float* hi = &s_h[i*3];
            float mi = s_m[i];
            float Ivt[3], Iat[3], hxv[3], hxa[3];
            mv3(Ai, nw, Ivt);  cross3(hi, nvl, hxv);
            mv3(Ai, naw, Iat); cross3(hi, nav, hxa);
#pragma unroll
            for (int k = 0; k < 3; k++){ Ivt[k] += hxv[k]; Iat[k] += hxa[k]; }
            float hxw[3], hxaw[3];
            cross3(hi, nw, hxw); cross3(hi, naw, hxaw);
            float Ivb[3] = { mi*nvl[0]-hxw[0], mi*nvl[1]-hxw[1], mi*nvl[2]-hxw[2] };
            float Iab[3] = { mi*nav[0]-hxaw[0], mi*nav[1]-hxaw[1], mi*nav[2]-hxaw[2] };
            float c1[3], c2[3], c3[3];
            cross3(nw, Ivt, c1); cross3(nvl, Ivb, c2); cross3(nw, Ivb, c3);
            FF[i][0] = Iat[0]+c1[0]+c2[0];
            FF[i][1] = Iat[1]+c1[1]+c2[1];
            FF[i][2] = Iat[2]+c1[2]+c2[2];
            FF[i][3] = Iab[0]+c3[0];
            FF[i][4] = Iab[1]+c3[1];
            FF[i][5] = Iab[2]+c3[2];
#pragma unroll
            for (int k = 0; k < 3; k++){ w[k]=nw[k]; vl[k]=nvl[k]; aw[k]=naw[k]; av[k]=nav[k]; }
        }
        // backward fold: rhs[i] = u_i - a . f_i_top
#pragma unroll
        for (int i = NJ-1; i >= 0; i--){
            const float* a = &s_ax[i*3];
            rhs[i] -= a[0]*FF[i][0] + a[1]*FF[i][1] + a[2]*FF[i][2];
            if (i > 0){
                const float* p = &s_pt[i*3];
                float E[9]; makeE(a, sn[i], cs[i], &s_Rt[i*9], E);
                float tm[3], tf[3], cp[3];
                mtv3(E, &FF[i][0], tm); mtv3(E, &FF[i][3], tf);
                cross3(p, tf, cp);
                FF[i-1][0]+=tm[0]+cp[0]; FF[i-1][1]+=tm[1]+cp[1]; FF[i-1][2]+=tm[2]+cp[2];
                FF[i-1][3]+=tf[0];       FF[i-1][4]+=tf[1];       FF[i-1][5]+=tf[2];
            }
        }
    }

    __syncthreads();

    if (act && role == 0){
        // =================== Cholesky solve + integrate ===================
        float Mx[28];
#pragma unroll
        for (int j = 0; j < 28; j++) Mx[j] = s_M[lane*MPAD + j];
#pragma unroll
        for (int i = 0; i < NJ; i++) Mx[MIX(i,i)] += 1e-8f;

#pragma unroll
        for (int k = 0; k < NJ; k++){
            float d = Mx[MIX(k,k)];
#pragma unroll
            for (int j = 0; j < NJ; j++) if (j < k) d -= Mx[MIX(k,j)]*Mx[MIX(k,j)];
            float linv = __builtin_amdgcn_rsqf(d);
            Mx[MIX(k,k)] = linv;
#pragma unroll
            for (int i = k+1; i < NJ; i++){
                float s2 = Mx[MIX(i,k)];
#pragma unroll
                for (int j = 0; j < NJ; j++) if (j < k) s2 -= Mx[MIX(i,j)]*Mx[MIX(k,j)];
                Mx[MIX(i,k)] = s2 * linv;
            }
        }
        float y[NJ];
#pragma unroll
        for (int i = 0; i < NJ; i++){
            float s2 = rhs[i];
#pragma unroll
            for (int j = 0; j < NJ; j++) if (j < i) s2 -= Mx[MIX(i,j)]*y[j];
            y[i] = s2 * Mx[MIX(i,i)];
        }
        float z[NJ];
#pragma unroll
        for (int i = NJ-1; i >= 0; i--){
            float s2 = y[i];
#pragma unroll
            for (int j = NJ-1; j >= 0; j--) if (j > i) s2 -= Mx[MIX(j,i)]*z[j];
            z[i] = s2 * Mx[MIX(i,i)];
        }

        float o14[14];
#pragma unroll
        for (int i = 0; i < NJ; i++){
            float qdn = qd[i] + DTF*z[i];
            o14[i]      = q[i] + DTF*qdn;
            o14[NJ + i] = qdn;
        }
        float2* o2 = (float2*)(out + e*14);
#pragma unroll
        for (int i = 0; i < 7; i++){ float2 v; v.x = o14[2*i]; v.y = o14[2*i+1]; o2[i] = v; }
    }
}

extern "C" void kernel_launch(void* const* d_in, const int* in_sizes, int n_in,
                              void* d_out, int out_size, void* d_ws, size_t ws_size,
                              hipStream_t stream) {
    const float* x   = (const float*)d_in[0];
    const float* u   = (const float*)d_in[1];
    const float* ax  = (const float*)d_in[2];
    const float* Rt  = (const float*)d_in[3];
    const float* pt  = (const float*)d_in[4];
    const float* Isp = (const float*)d_in[5];
    float* out = (float*)d_out;
    int B = in_sizes[0] / 14;
    int grid = (B + 63) / 64;
    hipLaunchKernelGGL(panda_step, dim3(grid), dim3(128), 0, stream,
                       x, u, ax, Rt, pt, Isp, out, B);
}